// Round 3
// baseline (23.797 us; speedup 1.0000x reference)
//
#include <hip/hip_runtime.h>

// GGNN: N=18, C=4, A=14, H=20, O=8, T=5. One fused single-block kernel.
// R3: LDS-instruction-minimized. h/aa/r stored ROW-major so all hot reads are
// ds_read_b128 (float4). aa padded to stride 44 (breaks stride-40 bank alias).
// One thread owns (i,n) and computes z, r, AND the Ww.a partial (reads aa/h
// rows once); z + w-partial live in registers across the P2->P3 barrier.
// Adjacency row/col in registers for P1. 384 threads = 6 waves.

#define AS 44   // aa row stride (padded from 40)

__device__ __forceinline__ float fsig(float x){ return 1.0f/(1.0f+__expf(-x)); }
__device__ __forceinline__ float ftnh(float x){ return 1.0f - 2.0f/(__expf(2.0f*x)+1.0f); }

__global__ __launch_bounds__(384, 1) void ggnn_fused(
    const float* __restrict__ x,  const float* __restrict__ adj,
    const float* __restrict__ Wz, const float* __restrict__ bz,
    const float* __restrict__ Uz, const float* __restrict__ buz,
    const float* __restrict__ Wr, const float* __restrict__ br,
    const float* __restrict__ Ur, const float* __restrict__ bur,
    const float* __restrict__ Ww, const float* __restrict__ bw,
    const float* __restrict__ Uw, const float* __restrict__ bu,
    const float* __restrict__ Wo, const float* __restrict__ bo,
    const float* __restrict__ Wx, const float* __restrict__ bx,
    const float* __restrict__ Wy, const float* __restrict__ by,
    const float* __restrict__ w2, const float* __restrict__ b2,
    float* __restrict__ outp)
{
  __shared__ __align__(16) float hA[360], hB[360];     // h row-major [18][20]
  __shared__ __align__(16) float aaL[18*AS];           // a row-major [18][44-pad]
  __shared__ __align__(16) float rrL[360];             // r row-major [18][20]
  __shared__ float sAdj[324];
  __shared__ __align__(16) float sOut[144], sCf[32], sAf[112], sRfc[56];

  const int tid = threadIdx.x;

  // ---- P2/P3 mapping: thread owns (i, n), all gates ----
  const bool act2 = (tid < 360);
  const int i2 = tid / 18;           // 0..19
  const int n2 = tid % 18;

  // ---- P1 mapping: tid<180 -> (n1, q1); q1<5 = in-half, q1>=5 = out-half ----
  const bool act1 = (tid < 180);
  const int n1 = tid / 10;
  const int q1 = tid % 10;
  const int hoff1 = 4 * (q1 % 5);    // h dword offset for this segment

  // ---- staging: h0 = x (row-major copy), sAdj ----
  if (tid < 90) ((float4*)hA)[tid] = ((const float4*)x)[tid];
  if (tid < 324) sAdj[tid] = adj[tid];

  // ---- adjacency row/col into registers (P1 threads) ----
  float adjv[18];
  if (act1) {
    #pragma unroll
    for (int m = 0; m < 18; ++m)
      adjv[m] = (q1 < 5) ? adj[n1*18 + m] : adj[m*18 + n1];
  }

  // ---- GRU weights into registers (reused all 5 steps) ----
  float4 wz4[10], wr4[10], ww4[10], uz4[5], ur4[5], uw4[5];
  float bzz=0.f, brr=0.f, bww=0.f, bui=0.f;
  if (act2) {
    #pragma unroll
    for (int q=0;q<10;q++){
      wz4[q] = ((const float4*)(Wz + i2*40))[q];
      wr4[q] = ((const float4*)(Wr + i2*40))[q];
      ww4[q] = ((const float4*)(Ww + i2*40))[q];
    }
    #pragma unroll
    for (int q=0;q<5;q++){
      uz4[q] = ((const float4*)(Uz + i2*20))[q];
      ur4[q] = ((const float4*)(Ur + i2*20))[q];
      uw4[q] = ((const float4*)(Uw + i2*20))[q];
    }
    bzz = bz[i2] + buz[i2];
    brr = br[i2] + bur[i2];
    bww = bw[i2];
    bui = bu[i2];
  }
  __syncthreads();

  float* hc = hA;
  float* hn = hB;
  float zreg = 0.f, swreg = 0.f;

  for (int t = 0; t < 5; ++t) {
    // ---- P1: aa[n][4q..4q+3] = sum_m adj(row/col) * h[m][seg] ----
    if (act1) {
      float4 acc = make_float4(0.f,0.f,0.f,0.f);
      #pragma unroll
      for (int m = 0; m < 18; ++m) {
        float4 h4 = *(const float4*)&hc[m*20 + hoff1];
        float av = adjv[m];
        acc.x += av*h4.x; acc.y += av*h4.y; acc.z += av*h4.z; acc.w += av*h4.w;
      }
      *(float4*)&aaL[n1*AS + 4*q1] = acc;
    }
    __syncthreads();

    // ---- P2: z, r, and Ww.a partial for (i2, n2); aa/h rows read once ----
    if (act2) {
      float sz = bzz, sr = brr, sw = bww;
      const float4* ar = (const float4*)&aaL[n2*AS];
      #pragma unroll
      for (int q=0;q<10;q++){
        float4 a4 = ar[q];
        sz += wz4[q].x*a4.x + wz4[q].y*a4.y + wz4[q].z*a4.z + wz4[q].w*a4.w;
        sr += wr4[q].x*a4.x + wr4[q].y*a4.y + wr4[q].z*a4.z + wr4[q].w*a4.w;
        sw += ww4[q].x*a4.x + ww4[q].y*a4.y + ww4[q].z*a4.z + ww4[q].w*a4.w;
      }
      const float4* hr = (const float4*)&hc[n2*20];
      #pragma unroll
      for (int q=0;q<5;q++){
        float4 h4 = hr[q];
        sz += uz4[q].x*h4.x + uz4[q].y*h4.y + uz4[q].z*h4.z + uz4[q].w*h4.w;
        sr += ur4[q].x*h4.x + ur4[q].y*h4.y + ur4[q].z*h4.z + ur4[q].w*h4.w;
      }
      zreg  = fsig(sz);
      swreg = sw;
      rrL[n2*20 + i2] = fsig(sr);
    }
    __syncthreads();

    // ---- P3: candidate + h update ----
    if (act2) {
      float s = swreg + bui;
      const float4* rr4 = (const float4*)&rrL[n2*20];
      const float4* hr  = (const float4*)&hc[n2*20];
      #pragma unroll
      for (int q=0;q<5;q++){
        float4 r4 = rr4[q];
        float4 h4 = hr[q];
        s += uw4[q].x*r4.x*h4.x + uw4[q].y*r4.y*h4.y
           + uw4[q].z*r4.z*h4.z + uw4[q].w*r4.w*h4.w;
      }
      float hg = ftnh(s);
      float hv = hc[n2*20 + i2];
      hn[n2*20 + i2] = (1.f - zreg)*hv + zreg*hg;
    }
    __syncthreads();
    float* tmp = hc; hc = hn; hn = tmp;
  }

  // ---- epilogue ----
  if (tid < 144) {                                 // out[n][o]
    int n_ = tid/8, o = tid%8;
    const float4* hr = (const float4*)&hc[n_*20];
    const float4* wo = (const float4*)(Wo + o*40);
    const float4* xv = (const float4*)(x + n_*20);
    float s = bo[o];
    #pragma unroll
    for (int q=0;q<5;q++){
      float4 w = wo[q],  h4 = hr[q];
      s += w.x*h4.x + w.y*h4.y + w.z*h4.z + w.w*h4.w;
      float4 w2_ = wo[5+q], x4 = xv[q];
      s += w2_.x*x4.x + w2_.y*x4.y + w2_.z*x4.z + w2_.w*x4.w;
    }
    sOut[tid] = ftnh(s);
  } else if (tid >= 144 && tid < 176) {            // cfcx [4][8]
    int ii = tid-144; int c = ii/8, o = ii%8;
    const float4* hr = (const float4*)&hc[c*20];
    const float4* wx = (const float4*)(Wx + o*20);
    float s = bx[o];
    #pragma unroll
    for (int q=0;q<5;q++){
      float4 w = wx[q], h4 = hr[q];
      s += w.x*h4.x + w.y*h4.y + w.z*h4.z + w.w*h4.w;
    }
    sCf[ii] = ftnh(s);
  } else if (tid >= 176 && tid < 288) {            // afcy [14][8]
    int ii = tid-176; int a = ii/8, o = ii%8;
    const float4* hr = (const float4*)&hc[(4+a)*20];
    const float4* wy = (const float4*)(Wy + o*20);
    float s = by[o];
    #pragma unroll
    for (int q=0;q<5;q++){
      float4 w = wy[q], h4 = hr[q];
      s += w.x*h4.x + w.y*h4.y + w.z*h4.z + w.w*h4.w;
    }
    sAf[ii] = ftnh(s);
  }
  __syncthreads();

  if (tid < 56) {                                  // rfc[c][a]
    int c = tid/14, a = tid%14;
    float4 w20 = ((const float4*)w2)[0];
    float4 w21 = ((const float4*)w2)[1];
    const float* cf = &sCf[c*8];
    const float* af = &sAf[a*8];
    float s = b2[0];
    s += cf[0]*af[0]*w20.x + cf[1]*af[1]*w20.y + cf[2]*af[2]*w20.z + cf[3]*af[3]*w20.w;
    s += cf[4]*af[4]*w21.x + cf[5]*af[5]*w21.y + cf[6]*af[6]*w21.z + cf[7]*af[7]*w21.w;
    sRfc[tid] = fsig(s) * sAdj[c*18 + 4 + a];
  }
  __syncthreads();

  for (int o = tid; o < 480; o += 384) {           // final [4][15][8]
    int c = o/120, rem = o%120, s_ = rem/8, oo = rem%8;
    float v = (s_ == 0) ? sOut[c*8+oo]
                        : sOut[(3+s_)*8+oo] * sRfc[c*14 + (s_-1)];
    outp[o] = v;
  }
}

extern "C" void kernel_launch(void* const* d_in, const int* in_sizes, int n_in,
                              void* d_out, int out_size, void* d_ws, size_t ws_size,
                              hipStream_t stream) {
  (void)in_sizes; (void)n_in; (void)d_ws; (void)ws_size; (void)out_size;
  const float* x   = (const float*)d_in[0];
  const float* adj = (const float*)d_in[1];
  const float* Wz  = (const float*)d_in[2];
  const float* bz  = (const float*)d_in[3];
  const float* Uz  = (const float*)d_in[4];
  const float* buz = (const float*)d_in[5];
  const float* Wr  = (const float*)d_in[6];
  const float* br  = (const float*)d_in[7];
  const float* Ur  = (const float*)d_in[8];
  const float* bur = (const float*)d_in[9];
  const float* Ww  = (const float*)d_in[10];
  const float* bw  = (const float*)d_in[11];
  const float* Uw  = (const float*)d_in[12];
  const float* bu  = (const float*)d_in[13];
  const float* Wo  = (const float*)d_in[14];
  const float* bo  = (const float*)d_in[15];
  const float* Wx  = (const float*)d_in[16];
  const float* bx  = (const float*)d_in[17];
  const float* Wy  = (const float*)d_in[18];
  const float* by  = (const float*)d_in[19];
  const float* w2  = (const float*)d_in[20];
  const float* b2  = (const float*)d_in[21];
  float* outp = (float*)d_out;

  ggnn_fused<<<1, 384, 0, stream>>>(x, adj, Wz, bz, Uz, buz, Wr, br, Ur, bur,
                                    Ww, bw, Uw, bu, Wo, bo, Wx, bx, Wy, by,
                                    w2, b2, outp);
}

// Round 4
// 21.265 us; speedup vs baseline: 1.1190x; 1.1190x over previous
//
#include <hip/hip_runtime.h>

// GGNN: N=18, C=4, A=14, H=20, O=8, T=5. One fused single-block kernel.
// R4 = R2 skeleton (768 thr = 12 waves, 2-gate wave-parity split, weights in
// registers) + vectorized LDS (row-major aa/h/r read as ds_read_b128).
// hT[k][m] single-buffer feeds P1 (broadcast reads); hR[n][j] double-buffered
// feeds P2/P3 row reads. adj row/col hoisted to registers for P1.

#define AS 44   // aa row stride (pad from 40; stride%32=12 -> <=3-way alias)
#define HS 20   // h/r row stride (80B, 16B-aligned rows)

__device__ __forceinline__ float fsig(float x){ return 1.0f/(1.0f+__expf(-x)); }
__device__ __forceinline__ float ftnh(float x){ return 1.0f - 2.0f/(__expf(2.0f*x)+1.0f); }
__device__ __forceinline__ float dot4(float4 a, float4 b){
  return a.x*b.x + a.y*b.y + a.z*b.z + a.w*b.w;
}

__global__ __launch_bounds__(768, 3) void ggnn_fused(
    const float* __restrict__ x,  const float* __restrict__ adj,
    const float* __restrict__ Wz, const float* __restrict__ bz,
    const float* __restrict__ Uz, const float* __restrict__ buz,
    const float* __restrict__ Wr, const float* __restrict__ br,
    const float* __restrict__ Ur, const float* __restrict__ bur,
    const float* __restrict__ Ww, const float* __restrict__ bw,
    const float* __restrict__ Uw, const float* __restrict__ bu,
    const float* __restrict__ Wo, const float* __restrict__ bo,
    const float* __restrict__ Wx, const float* __restrict__ bx,
    const float* __restrict__ Wy, const float* __restrict__ by,
    const float* __restrict__ w2, const float* __restrict__ b2,
    float* __restrict__ outp)
{
  __shared__ float sAdj[324];
  __shared__ __align__(16) float hT[20*HS];          // hT[k][m], m<18 (pad 20)
  __shared__ __align__(16) float hRA[18*HS], hRB[18*HS];
  __shared__ __align__(16) float aaR[18*AS];
  __shared__ __align__(16) float rrR[18*HS];
  __shared__ float ws1[18*HS];
  __shared__ __align__(16) float sOut[144], sCf[32], sAf[112], sRfc[56];

  const int tid = threadIdx.x;

  // P2/P3 mapping: gate g = wave parity; idx over (i2,n2), n2 fastest.
  const int g   = (tid >> 6) & 1;
  const int idx = (tid >> 7) * 64 + (tid & 63);
  const bool act2 = (idx < 360);
  const int i2 = idx / 18, n2 = idx % 18;

  // P1 mapping: tid<720 -> (kk, n1); kk<20 = in-half (adj row), else out-half.
  const bool act1 = (tid < 720);
  const int n1 = tid % 18;
  const int kk = tid / 18;                       // 0..39
  const int k1 = (kk < 20) ? kk : (kk - 20);

  // ---- staging ----
  if (tid < 324) sAdj[tid] = adj[tid];
  if (tid < 90)  ((float4*)hRA)[tid] = ((const float4*)x)[tid];
  if (tid < 360) { int j = tid/18, n = tid%18; hT[j*HS+n] = x[n*20+j]; }

  // adjacency row/col into registers (P1 threads)
  float adjv[18];
  if (act1) {
    #pragma unroll
    for (int m = 0; m < 18; ++m)
      adjv[m] = (kk < 20) ? adj[n1*18 + m] : adj[m*18 + n1];
  }

  // ---- GRU weights in registers (2-gate split keeps ~<=110 VGPR) ----
  float4 w4[10], wh4[5], u4[5], uw4[5];
  float bias1 = 0.f, bwi = 0.f, bui = 0.f;
  if (act2) {
    const float* Wg = g ? Wr : Wz;
    const float* Ug = g ? Ur : Uz;
    #pragma unroll
    for (int q=0;q<10;q++) w4[q] = *(const float4*)(Wg + i2*40 + 4*q);
    #pragma unroll
    for (int q=0;q<5;q++){
      u4[q]  = *(const float4*)(Ug + i2*20 + 4*q);
      wh4[q] = *(const float4*)(Ww + i2*40 + g*20 + 4*q);
    }
    if (g == 0){
      bias1 = bz[i2] + buz[i2];
      bwi   = bw[i2];
      bui   = bu[i2];
      #pragma unroll
      for (int q=0;q<5;q++) uw4[q] = *(const float4*)(Uw + i2*20 + 4*q);
    } else {
      bias1 = br[i2] + bur[i2];
    }
  }
  __syncthreads();

  float* hc = hRA;
  float* hn = hRB;
  float zreg = 0.f, swreg = 0.f;

  for (int t = 0; t < 5; ++t) {
    // ---- P1: aaR[n1][kk] = sum_m adj(row/col)[m] * hT[k1][m] ----
    if (act1) {
      const float* hrow = &hT[k1*HS];            // broadcast across n1 lanes
      float4 t0 = *(const float4*)(hrow + 0);
      float4 t1 = *(const float4*)(hrow + 4);
      float4 t2 = *(const float4*)(hrow + 8);
      float4 t3 = *(const float4*)(hrow + 12);
      float  ta = hrow[16], tb = hrow[17];
      float s = 0.f;
      s += adjv[0]*t0.x + adjv[1]*t0.y + adjv[2]*t0.z + adjv[3]*t0.w;
      s += adjv[4]*t1.x + adjv[5]*t1.y + adjv[6]*t1.z + adjv[7]*t1.w;
      s += adjv[8]*t2.x + adjv[9]*t2.y + adjv[10]*t2.z + adjv[11]*t2.w;
      s += adjv[12]*t3.x + adjv[13]*t3.y + adjv[14]*t3.z + adjv[15]*t3.w;
      s += adjv[16]*ta + adjv[17]*tb;
      aaR[n1*AS + kk] = s;
    }
    __syncthreads();

    // ---- P2: gate pre-activations, all reads ds_read_b128 ----
    if (act2) {
      const float4* ar = (const float4*)&aaR[n2*AS];
      const float4* hr = (const float4*)&hc[n2*HS];
      float sg = bias1;
      #pragma unroll
      for (int q=0;q<10;q++) sg += dot4(w4[q], ar[q]);
      #pragma unroll
      for (int q=0;q<5;q++)  sg += dot4(u4[q], hr[q]);
      const float4* arw = ar + (g ? 5 : 0);
      float sw = bwi;
      #pragma unroll
      for (int q=0;q<5;q++)  sw += dot4(wh4[q], arw[q]);
      if (g == 0){
        zreg  = fsig(sg);                        // live across barrier in regs
        swreg = sw;
      } else {
        rrR[n2*HS + i2] = fsig(sg);
        ws1[n2*HS + i2] = sw;
      }
    }
    __syncthreads();

    // ---- P3: candidate + h update (g0 waves) ----
    if (g == 0 && act2) {
      float s = swreg + ws1[n2*HS + i2] + bui;
      const float4* rr4 = (const float4*)&rrR[n2*HS];
      const float4* hr  = (const float4*)&hc[n2*HS];
      #pragma unroll
      for (int q=0;q<5;q++){
        float4 r4 = rr4[q];
        float4 h4 = hr[q];
        s += uw4[q].x*r4.x*h4.x + uw4[q].y*r4.y*h4.y
           + uw4[q].z*r4.z*h4.z + uw4[q].w*r4.w*h4.w;
      }
      float hg = ftnh(s);
      float hv = hc[n2*HS + i2];
      float hnv = (1.f - zreg)*hv + zreg*hg;
      hn[n2*HS + i2] = hnv;                      // write OTHER hR buffer
      hT[i2*HS + n2] = hnv;                      // hT: no readers this phase
    }
    __syncthreads();
    float* tmp = hc; hc = hn; hn = tmp;
  }

  // ---- epilogue ----
  if (tid < 144) {                               // out[n][o]
    int n_ = tid/8, o = tid%8;
    const float4* hr = (const float4*)&hc[n_*HS];
    const float4* wo = (const float4*)(Wo + o*40);
    const float4* xv = (const float4*)(x + n_*20);
    float s = bo[o];
    #pragma unroll
    for (int q=0;q<5;q++){
      s += dot4(wo[q],   hr[q]);
      s += dot4(wo[5+q], xv[q]);
    }
    sOut[tid] = ftnh(s);
  } else if (tid >= 144 && tid < 176) {          // cfcx [4][8]
    int ii = tid-144; int c = ii/8, o = ii%8;
    const float4* hr = (const float4*)&hc[c*HS];
    const float4* wx = (const float4*)(Wx + o*20);
    float s = bx[o];
    #pragma unroll
    for (int q=0;q<5;q++) s += dot4(wx[q], hr[q]);
    sCf[ii] = ftnh(s);
  } else if (tid >= 176 && tid < 288) {          // afcy [14][8]
    int ii = tid-176; int a = ii/8, o = ii%8;
    const float4* hr = (const float4*)&hc[(4+a)*HS];
    const float4* wy = (const float4*)(Wy + o*20);
    float s = by[o];
    #pragma unroll
    for (int q=0;q<5;q++) s += dot4(wy[q], hr[q]);
    sAf[ii] = ftnh(s);
  }
  __syncthreads();

  if (tid < 56) {                                // rfc[c][a]
    int c = tid/14, a = tid%14;
    float4 w20 = ((const float4*)w2)[0];
    float4 w21 = ((const float4*)w2)[1];
    const float* cf = &sCf[c*8];
    const float* af = &sAf[a*8];
    float s = b2[0];
    s += cf[0]*af[0]*w20.x + cf[1]*af[1]*w20.y + cf[2]*af[2]*w20.z + cf[3]*af[3]*w20.w;
    s += cf[4]*af[4]*w21.x + cf[5]*af[5]*w21.y + cf[6]*af[6]*w21.z + cf[7]*af[7]*w21.w;
    sRfc[tid] = fsig(s) * sAdj[c*18 + 4 + a];
  }
  __syncthreads();

  if (tid < 480) {                               // final [4][15][8]
    int c = tid/120, rem = tid%120, s_ = rem/8, oo = rem%8;
    float v = (s_ == 0) ? sOut[c*8+oo]
                        : sOut[(3+s_)*8+oo] * sRfc[c*14 + (s_-1)];
    outp[tid] = v;
  }
}

extern "C" void kernel_launch(void* const* d_in, const int* in_sizes, int n_in,
                              void* d_out, int out_size, void* d_ws, size_t ws_size,
                              hipStream_t stream) {
  (void)in_sizes; (void)n_in; (void)d_ws; (void)ws_size; (void)out_size;
  const float* x   = (const float*)d_in[0];
  const float* adj = (const float*)d_in[1];
  const float* Wz  = (const float*)d_in[2];
  const float* bz  = (const float*)d_in[3];
  const float* Uz  = (const float*)d_in[4];
  const float* buz = (const float*)d_in[5];
  const float* Wr  = (const float*)d_in[6];
  const float* br  = (const float*)d_in[7];
  const float* Ur  = (const float*)d_in[8];
  const float* bur = (const float*)d_in[9];
  const float* Ww  = (const float*)d_in[10];
  const float* bw  = (const float*)d_in[11];
  const float* Uw  = (const float*)d_in[12];
  const float* bu  = (const float*)d_in[13];
  const float* Wo  = (const float*)d_in[14];
  const float* bo  = (const float*)d_in[15];
  const float* Wx  = (const float*)d_in[16];
  const float* bx  = (const float*)d_in[17];
  const float* Wy  = (const float*)d_in[18];
  const float* by  = (const float*)d_in[19];
  const float* w2  = (const float*)d_in[20];
  const float* b2  = (const float*)d_in[21];
  float* outp = (float*)d_out;

  ggnn_fused<<<1, 768, 0, stream>>>(x, adj, Wz, bz, Uz, buz, Wr, br, Ur, bur,
                                    Ww, bw, Uw, bu, Wo, bo, Wx, bx, Wy, by,
                                    w2, b2, outp);
}

// Round 5
// 20.926 us; speedup vs baseline: 1.1372x; 1.0162x over previous
//
#include <hip/hip_runtime.h>

// GGNN: N=18, C=4, A=14, H=20, O=8, T=5. One fused single-block kernel.
// R5: wave-confined dataflow. Node n -> 20 lanes of one wave (3 nodes/wave,
// 6 waves, 384 thr). Thread (n,j) computes aa[n][j] AND all 3 gates for i=j
// (weight rows for j in registers). aa / v=r*h / hR are wave-private ->
// intra-wave s_waitcnt sync instead of barriers. Only hT (transposed h, read
// cross-wave in P1) is double-buffered behind ONE __syncthreads per step.

__device__ __forceinline__ float fsig(float x){ return 1.0f/(1.0f+__expf(-x)); }
__device__ __forceinline__ float ftnh(float x){ return 1.0f - 2.0f/(__expf(2.0f*x)+1.0f); }
__device__ __forceinline__ float dot4(float4 a, float4 b){
  return a.x*b.x + a.y*b.y + a.z*b.z + a.w*b.w;
}
// Intra-wave producer->consumer LDS ordering: drain this wave's LDS ops and
// forbid compiler motion across (rule #18: memory clobber + sched_barrier).
#define WAVE_SYNC() do { asm volatile("s_waitcnt lgkmcnt(0)" ::: "memory"); \
                         __builtin_amdgcn_sched_barrier(0); } while(0)

__global__ __launch_bounds__(384, 1) void ggnn_fused(
    const float* __restrict__ x,  const float* __restrict__ adj,
    const float* __restrict__ Wz, const float* __restrict__ bz,
    const float* __restrict__ Uz, const float* __restrict__ buz,
    const float* __restrict__ Wr, const float* __restrict__ br,
    const float* __restrict__ Ur, const float* __restrict__ bur,
    const float* __restrict__ Ww, const float* __restrict__ bw,
    const float* __restrict__ Uw, const float* __restrict__ bu,
    const float* __restrict__ Wo, const float* __restrict__ bo,
    const float* __restrict__ Wx, const float* __restrict__ bx,
    const float* __restrict__ Wy, const float* __restrict__ by,
    const float* __restrict__ w2, const float* __restrict__ b2,
    float* __restrict__ outp)
{
  __shared__ float sAdj[324];
  __shared__ __align__(16) float hR[360];            // h row-major [18][20] (wave-private rows)
  __shared__ __align__(16) float hT0[400], hT1[400]; // h transposed [20][20] (m<18 + zero pad)
  __shared__ __align__(16) float aaR[720];           // aa row-major [18][40] (wave-private rows)
  __shared__ __align__(16) float vR[360];            // r*h row-major [18][20] (wave-private)
  __shared__ __align__(16) float sOut[144], sCf[32], sAf[112], sRfc[56];

  const int tid  = threadIdx.x;
  const int lane = tid & 63;
  const int wave = tid >> 6;
  const bool act = (lane < 60);
  const int n = wave*3 + lane/20;      // node 0..17
  const int j = lane % 20;             // feature / gate row 0..19

  // ---- staging ----
  if (tid < 324) sAdj[tid] = adj[tid];
  if (tid < 90)  ((float4*)hR)[tid] = ((const float4*)x)[tid];
  for (int s2 = tid; s2 < 400; s2 += 384) {          // hT0 = x^T, pad cols zeroed
    int jj = s2/20, mm = s2%20;
    hT0[s2] = (mm < 18) ? x[mm*20 + jj] : 0.f;
  }
  if (tid < 40) { int jj = tid>>1, mm = 18 + (tid&1); hT1[jj*20+mm] = 0.f; }

  // ---- per-thread weights (row i=j) + adjacency row/col in registers ----
  float4 wz[10], wr[10], ww[10], uz[5], ur[5], uw[5];
  float bzz=0.f, brr=0.f, bwi=0.f, bui=0.f;
  float adin[20], adout[20];
  if (act) {
    #pragma unroll
    for (int q=0;q<10;q++){
      wz[q] = *(const float4*)(Wz + j*40 + 4*q);
      wr[q] = *(const float4*)(Wr + j*40 + 4*q);
      ww[q] = *(const float4*)(Ww + j*40 + 4*q);
    }
    #pragma unroll
    for (int q=0;q<5;q++){
      uz[q] = *(const float4*)(Uz + j*20 + 4*q);
      ur[q] = *(const float4*)(Ur + j*20 + 4*q);
      uw[q] = *(const float4*)(Uw + j*20 + 4*q);
    }
    bzz = bz[j] + buz[j];
    brr = br[j] + bur[j];
    bwi = bw[j];
    bui = bu[j];
    #pragma unroll
    for (int m=0;m<18;m++){ adin[m] = adj[n*18+m]; adout[m] = adj[m*18+n]; }
    adin[18]=adin[19]=adout[18]=adout[19]=0.f;
  }
  __syncthreads();

  const float* hTc = hT0;
  float*       hTn = hT1;

  for (int t = 0; t < 5; ++t) {
    if (act) {
      // ---- P1: aa[n][j] (in) and aa[n][20+j] (out), h columns via hT rows ----
      const float* hTr = hTc + j*20;
      float si = 0.f, so = 0.f;
      #pragma unroll
      for (int q=0;q<5;q++){
        float4 h4 = *(const float4*)(hTr + 4*q);
        si += adin[4*q+0]*h4.x + adin[4*q+1]*h4.y + adin[4*q+2]*h4.z + adin[4*q+3]*h4.w;
        so += adout[4*q+0]*h4.x + adout[4*q+1]*h4.y + adout[4*q+2]*h4.z + adout[4*q+3]*h4.w;
      }
      float* ap = &aaR[n*40 + j];
      ap[0]  = si;
      ap[20] = so;
      WAVE_SYNC();

      // ---- P2: z, r, Ww.a for i=j (aa/h rows wave-local, read once) ----
      const float4* ar = (const float4*)&aaR[n*40];
      const float4* hr = (const float4*)&hR[n*20];
      float sz = bzz, sr = brr, sw = bwi;
      #pragma unroll
      for (int q=0;q<10;q++){
        float4 a4 = ar[q];
        sz += dot4(wz[q], a4);
        sr += dot4(wr[q], a4);
        sw += dot4(ww[q], a4);
      }
      #pragma unroll
      for (int q=0;q<5;q++){
        float4 h4 = hr[q];
        sz += dot4(uz[q], h4);
        sr += dot4(ur[q], h4);
      }
      float hv = hR[n*20 + j];
      float zv = fsig(sz);
      float rv = fsig(sr);
      vR[n*20 + j] = rv * hv;
      WAVE_SYNC();

      // ---- P3: hg + h update ----
      const float4* vr = (const float4*)&vR[n*20];
      float s = sw + bui;
      #pragma unroll
      for (int q=0;q<5;q++) s += dot4(uw[q], vr[q]);
      float hg = ftnh(s);
      float hnv = (1.f - zv)*hv + zv*hg;
      hR[n*20 + j]  = hnv;          // wave-private: own lanes read it next step
      hTn[j*20 + n] = hnv;          // cross-wave: other buffer, behind barrier
    }
    __syncthreads();
    const float* tc = hTc; hTc = hTn; hTn = (float*)tc;
  }

  // ---- epilogue (h = hR rows, synced) ----
  if (tid < 144) {                               // out[n][o]
    int n_ = tid/8, o = tid%8;
    const float4* hr = (const float4*)&hR[n_*20];
    const float4* wo = (const float4*)(Wo + o*40);
    const float4* xv = (const float4*)(x + n_*20);
    float s = bo[o];
    #pragma unroll
    for (int q=0;q<5;q++){
      s += dot4(wo[q],   hr[q]);
      s += dot4(wo[5+q], xv[q]);
    }
    sOut[tid] = ftnh(s);
  } else if (tid >= 144 && tid < 176) {          // cfcx [4][8]
    int ii = tid-144; int c = ii/8, o = ii%8;
    const float4* hr = (const float4*)&hR[c*20];
    const float4* wx = (const float4*)(Wx + o*20);
    float s = bx[o];
    #pragma unroll
    for (int q=0;q<5;q++) s += dot4(wx[q], hr[q]);
    sCf[ii] = ftnh(s);
  } else if (tid >= 176 && tid < 288) {          // afcy [14][8]
    int ii = tid-176; int a = ii/8, o = ii%8;
    const float4* hr = (const float4*)&hR[(4+a)*20];
    const float4* wy = (const float4*)(Wy + o*20);
    float s = by[o];
    #pragma unroll
    for (int q=0;q<5;q++) s += dot4(wy[q], hr[q]);
    sAf[ii] = ftnh(s);
  }
  __syncthreads();

  if (tid < 56) {                                // rfc[c][a]
    int c = tid/14, a = tid%14;
    float4 w20 = ((const float4*)w2)[0];
    float4 w21 = ((const float4*)w2)[1];
    const float* cf = &sCf[c*8];
    const float* af = &sAf[a*8];
    float s = b2[0];
    s += cf[0]*af[0]*w20.x + cf[1]*af[1]*w20.y + cf[2]*af[2]*w20.z + cf[3]*af[3]*w20.w;
    s += cf[4]*af[4]*w21.x + cf[5]*af[5]*w21.y + cf[6]*af[6]*w21.z + cf[7]*af[7]*w21.w;
    sRfc[tid] = fsig(s) * sAdj[c*18 + 4 + a];
  }
  __syncthreads();

  for (int o = tid; o < 480; o += 384) {         // final [4][15][8]
    int c = o/120, rem = o%120, s_ = rem/8, oo = rem%8;
    float v = (s_ == 0) ? sOut[c*8+oo]
                        : sOut[(3+s_)*8+oo] * sRfc[c*14 + (s_-1)];
    outp[o] = v;
  }
}

extern "C" void kernel_launch(void* const* d_in, const int* in_sizes, int n_in,
                              void* d_out, int out_size, void* d_ws, size_t ws_size,
                              hipStream_t stream) {
  (void)in_sizes; (void)n_in; (void)d_ws; (void)ws_size; (void)out_size;
  const float* x   = (const float*)d_in[0];
  const float* adj = (const float*)d_in[1];
  const float* Wz  = (const float*)d_in[2];
  const float* bz  = (const float*)d_in[3];
  const float* Uz  = (const float*)d_in[4];
  const float* buz = (const float*)d_in[5];
  const float* Wr  = (const float*)d_in[6];
  const float* br  = (const float*)d_in[7];
  const float* Ur  = (const float*)d_in[8];
  const float* bur = (const float*)d_in[9];
  const float* Ww  = (const float*)d_in[10];
  const float* bw  = (const float*)d_in[11];
  const float* Uw  = (const float*)d_in[12];
  const float* bu  = (const float*)d_in[13];
  const float* Wo  = (const float*)d_in[14];
  const float* bo  = (const float*)d_in[15];
  const float* Wx  = (const float*)d_in[16];
  const float* bx  = (const float*)d_in[17];
  const float* Wy  = (const float*)d_in[18];
  const float* by  = (const float*)d_in[19];
  const float* w2  = (const float*)d_in[20];
  const float* b2  = (const float*)d_in[21];
  float* outp = (float*)d_out;

  ggnn_fused<<<1, 384, 0, stream>>>(x, adj, Wz, bz, Uz, buz, Wr, br, Ur, bur,
                                    Ww, bw, Uw, bu, Wo, bo, Wx, bx, Wy, by,
                                    w2, b2, outp);
}

// Round 6
// 20.217 us; speedup vs baseline: 1.1771x; 1.0351x over previous
//
#include <hip/hip_runtime.h>

// GGNN: N=18, C=4, A=14, H=20, O=8, T=5. One fused single-block kernel.
// R6 = R5 t-loop (wave-confined: node n -> 20 lanes, 3 nodes/wave, 6 waves;
// aa / v=r*h / hR wave-private with intra-wave s_waitcnt sync; hT
// double-buffered behind ONE barrier/step) + coalesced prologue:
// all weights staged global->LDS with float4 coalesced loads ONCE, then
// register-hoisted from LDS (rows padded to stride 44/24 to spread banks).

__device__ __forceinline__ float fsig(float x){ return 1.0f/(1.0f+__expf(-x)); }
__device__ __forceinline__ float ftnh(float x){ return 1.0f - 2.0f/(__expf(2.0f*x)+1.0f); }
__device__ __forceinline__ float dot4(float4 a, float4 b){
  return a.x*b.x + a.y*b.y + a.z*b.z + a.w*b.w;
}
// Intra-wave producer->consumer LDS ordering (rule #18).
#define WAVE_SYNC() do { asm volatile("s_waitcnt lgkmcnt(0)" ::: "memory"); \
                         __builtin_amdgcn_sched_barrier(0); } while(0)

__global__ __launch_bounds__(384, 1) void ggnn_fused(
    const float* __restrict__ x,  const float* __restrict__ adj,
    const float* __restrict__ Wz, const float* __restrict__ bz,
    const float* __restrict__ Uz, const float* __restrict__ buz,
    const float* __restrict__ Wr, const float* __restrict__ br,
    const float* __restrict__ Ur, const float* __restrict__ bur,
    const float* __restrict__ Ww, const float* __restrict__ bw,
    const float* __restrict__ Uw, const float* __restrict__ bu,
    const float* __restrict__ Wo, const float* __restrict__ bo,
    const float* __restrict__ Wx, const float* __restrict__ bx,
    const float* __restrict__ Wy, const float* __restrict__ by,
    const float* __restrict__ w2, const float* __restrict__ b2,
    float* __restrict__ outp)
{
  __shared__ float sAdj[324];
  __shared__ __align__(16) float hR[360];            // h row-major [18][20]
  __shared__ __align__(16) float hT0[400], hT1[400]; // h^T [20][20] (pad zeroed)
  __shared__ __align__(16) float aaR[720];           // aa row-major [18][40]
  __shared__ __align__(16) float vR[360];            // r*h row-major [18][20]
  __shared__ __align__(16) float sW[3*20*44];        // Wz,Wr,Ww rows pad->44
  __shared__ __align__(16) float sU[3*20*24];        // Uz,Ur,Uw rows pad->24
  __shared__ float sB[120];
  __shared__ __align__(16) float sOut[144], sCf[32], sAf[112], sRfc[56];

  const int tid  = threadIdx.x;
  const int lane = tid & 63;
  const int wave = tid >> 6;
  const bool act = (lane < 60);
  const int n = wave*3 + lane/20;      // node 0..17
  const int j = lane % 20;             // feature / gate row 0..19

  // ---- coalesced staging: weights -> LDS (once) ----
  if (tid < 200) {                     // W matrices: 200 float4 each
    int row = tid/10, col = (tid%10)*4;
    *(float4*)&sW[       row*44+col] = *(const float4*)(Wz + row*40+col);
    *(float4*)&sW[ 880 + row*44+col] = *(const float4*)(Wr + row*40+col);
    *(float4*)&sW[1760 + row*44+col] = *(const float4*)(Ww + row*40+col);
  } else if (tid < 300) {              // U matrices: 100 float4 each
    int i = tid-200; int row = i/5, col = (i%5)*4;
    *(float4*)&sU[      row*24+col] = *(const float4*)(Uz + row*20+col);
    *(float4*)&sU[480 + row*24+col] = *(const float4*)(Ur + row*20+col);
    *(float4*)&sU[960 + row*24+col] = *(const float4*)(Uw + row*20+col);
  } else if (tid < 320) {              // biases
    int i = tid-300;
    sB[i]=bz[i]; sB[20+i]=buz[i]; sB[40+i]=br[i];
    sB[60+i]=bur[i]; sB[80+i]=bw[i]; sB[100+i]=bu[i];
  }
  if (tid < 324) sAdj[tid] = adj[tid];
  if (tid < 90)  ((float4*)hR)[tid] = ((const float4*)x)[tid];
  for (int s2 = tid; s2 < 400; s2 += 384) {          // hT0 = x^T, pad zeroed
    int jj = s2/20, mm = s2%20;
    hT0[s2] = (mm < 18) ? x[mm*20 + jj] : 0.f;
  }
  if (tid < 40) { int jj = tid>>1, mm = 18 + (tid&1); hT1[jj*20+mm] = 0.f; }
  __syncthreads();

  // ---- register hoist from LDS (rows for gate i=j; adj row/col for n) ----
  float4 wz[10], wr[10], ww[10], uz[5], ur[5], uw[5];
  float bzz=0.f, brr=0.f, bwi=0.f, bui=0.f;
  float adin[20], adout[20];
  if (act) {
    const float4* pz = (const float4*)&sW[       j*44];
    const float4* pr = (const float4*)&sW[ 880 + j*44];
    const float4* pw = (const float4*)&sW[1760 + j*44];
    #pragma unroll
    for (int q=0;q<10;q++){ wz[q]=pz[q]; wr[q]=pr[q]; ww[q]=pw[q]; }
    const float4* qz = (const float4*)&sU[      j*24];
    const float4* qr = (const float4*)&sU[480 + j*24];
    const float4* qw = (const float4*)&sU[960 + j*24];
    #pragma unroll
    for (int q=0;q<5;q++){ uz[q]=qz[q]; ur[q]=qr[q]; uw[q]=qw[q]; }
    bzz = sB[j] + sB[20+j];
    brr = sB[40+j] + sB[60+j];
    bwi = sB[80+j];
    bui = sB[100+j];
    #pragma unroll
    for (int m=0;m<18;m++){ adin[m] = sAdj[n*18+m]; adout[m] = sAdj[m*18+n]; }
    adin[18]=adin[19]=adout[18]=adout[19]=0.f;
  }
  __syncthreads();

  const float* hTc = hT0;
  float*       hTn = hT1;

  for (int t = 0; t < 5; ++t) {
    if (act) {
      // ---- P1: aa[n][j] (in) and aa[n][20+j] (out) ----
      const float* hTr = hTc + j*20;
      float si = 0.f, so = 0.f;
      #pragma unroll
      for (int q=0;q<5;q++){
        float4 h4 = *(const float4*)(hTr + 4*q);
        si += adin[4*q+0]*h4.x + adin[4*q+1]*h4.y + adin[4*q+2]*h4.z + adin[4*q+3]*h4.w;
        so += adout[4*q+0]*h4.x + adout[4*q+1]*h4.y + adout[4*q+2]*h4.z + adout[4*q+3]*h4.w;
      }
      float* ap = &aaR[n*40 + j];
      ap[0]  = si;
      ap[20] = so;
      WAVE_SYNC();

      // ---- P2: z, r, Ww.a for i=j ----
      const float4* ar = (const float4*)&aaR[n*40];
      const float4* hr = (const float4*)&hR[n*20];
      float sz = bzz, sr = brr, sw = bwi;
      #pragma unroll
      for (int q=0;q<10;q++){
        float4 a4 = ar[q];
        sz += dot4(wz[q], a4);
        sr += dot4(wr[q], a4);
        sw += dot4(ww[q], a4);
      }
      #pragma unroll
      for (int q=0;q<5;q++){
        float4 h4 = hr[q];
        sz += dot4(uz[q], h4);
        sr += dot4(ur[q], h4);
      }
      float hv = hR[n*20 + j];
      float zv = fsig(sz);
      float rv = fsig(sr);
      vR[n*20 + j] = rv * hv;
      WAVE_SYNC();

      // ---- P3: hg + h update ----
      const float4* vr = (const float4*)&vR[n*20];
      float s = sw + bui;
      #pragma unroll
      for (int q=0;q<5;q++) s += dot4(uw[q], vr[q]);
      float hg = ftnh(s);
      float hnv = (1.f - zv)*hv + zv*hg;
      hR[n*20 + j]  = hnv;          // wave-private
      hTn[j*20 + n] = hnv;          // cross-wave, other buffer, behind barrier
    }
    __syncthreads();
    const float* tc = hTc; hTc = hTn; hTn = (float*)tc;
  }

  // ---- epilogue ----
  if (tid < 144) {                               // out[n][o]
    int n_ = tid/8, o = tid%8;
    const float4* hr = (const float4*)&hR[n_*20];
    const float4* wo = (const float4*)(Wo + o*40);
    const float4* xv = (const float4*)(x + n_*20);
    float s = bo[o];
    #pragma unroll
    for (int q=0;q<5;q++){
      s += dot4(wo[q],   hr[q]);
      s += dot4(wo[5+q], xv[q]);
    }
    sOut[tid] = ftnh(s);
  } else if (tid >= 144 && tid < 176) {          // cfcx [4][8]
    int ii = tid-144; int c = ii/8, o = ii%8;
    const float4* hr = (const float4*)&hR[c*20];
    const float4* wx = (const float4*)(Wx + o*20);
    float s = bx[o];
    #pragma unroll
    for (int q=0;q<5;q++) s += dot4(wx[q], hr[q]);
    sCf[ii] = ftnh(s);
  } else if (tid >= 176 && tid < 288) {          // afcy [14][8]
    int ii = tid-176; int a = ii/8, o = ii%8;
    const float4* hr = (const float4*)&hR[(4+a)*20];
    const float4* wy = (const float4*)(Wy + o*20);
    float s = by[o];
    #pragma unroll
    for (int q=0;q<5;q++) s += dot4(wy[q], hr[q]);
    sAf[ii] = ftnh(s);
  }
  __syncthreads();

  if (tid < 56) {                                // rfc[c][a]
    int c = tid/14, a = tid%14;
    float4 w20 = ((const float4*)w2)[0];
    float4 w21 = ((const float4*)w2)[1];
    const float* cf = &sCf[c*8];
    const float* af = &sAf[a*8];
    float s = b2[0];
    s += cf[0]*af[0]*w20.x + cf[1]*af[1]*w20.y + cf[2]*af[2]*w20.z + cf[3]*af[3]*w20.w;
    s += cf[4]*af[4]*w21.x + cf[5]*af[5]*w21.y + cf[6]*af[6]*w21.z + cf[7]*af[7]*w21.w;
    sRfc[tid] = fsig(s) * sAdj[c*18 + 4 + a];
  }
  __syncthreads();

  for (int o = tid; o < 480; o += 384) {         // final [4][15][8]
    int c = o/120, rem = o%120, s_ = rem/8, oo = rem%8;
    float v = (s_ == 0) ? sOut[c*8+oo]
                        : sOut[(3+s_)*8+oo] * sRfc[c*14 + (s_-1)];
    outp[o] = v;
  }
}

extern "C" void kernel_launch(void* const* d_in, const int* in_sizes, int n_in,
                              void* d_out, int out_size, void* d_ws, size_t ws_size,
                              hipStream_t stream) {
  (void)in_sizes; (void)n_in; (void)d_ws; (void)ws_size; (void)out_size;
  const float* x   = (const float*)d_in[0];
  const float* adj = (const float*)d_in[1];
  const float* Wz  = (const float*)d_in[2];
  const float* bz  = (const float*)d_in[3];
  const float* Uz  = (const float*)d_in[4];
  const float* buz = (const float*)d_in[5];
  const float* Wr  = (const float*)d_in[6];
  const float* br  = (const float*)d_in[7];
  const float* Ur  = (const float*)d_in[8];
  const float* bur = (const float*)d_in[9];
  const float* Ww  = (const float*)d_in[10];
  const float* bw  = (const float*)d_in[11];
  const float* Uw  = (const float*)d_in[12];
  const float* bu  = (const float*)d_in[13];
  const float* Wo  = (const float*)d_in[14];
  const float* bo  = (const float*)d_in[15];
  const float* Wx  = (const float*)d_in[16];
  const float* bx  = (const float*)d_in[17];
  const float* Wy  = (const float*)d_in[18];
  const float* by  = (const float*)d_in[19];
  const float* w2  = (const float*)d_in[20];
  const float* b2  = (const float*)d_in[21];
  float* outp = (float*)d_out;

  ggnn_fused<<<1, 384, 0, stream>>>(x, adj, Wz, bz, Uz, buz, Wr, br, Ur, bur,
                                    Ww, bw, Uw, bu, Wo, bo, Wx, bx, Wy, by,
                                    w2, b2, outp);
}